// Round 11
// baseline (148.618 us; speedup 1.0000x reference)
//
#include <hip/hip_runtime.h>
#include <cstdint>

typedef unsigned short u16;
typedef __bf16 bf16x8 __attribute__((ext_vector_type(8)));
typedef float f32x4 __attribute__((ext_vector_type(4)));

#define NB 8192          // batch rows
#define HD 512           // hidden
#define KD 1024          // IN + H
#define ND 2048          // 4H (physical, column-reordered)
#define HY_OFF (NB * HD) // offset of cy in d_out

// ---------- helpers ----------
__device__ __forceinline__ u16 f2bf(float f) {
  unsigned u = __float_as_uint(f);
  u += 0x7FFFu + ((u >> 16) & 1u);          // round-to-nearest-even bf16
  return (u16)(u >> 16);
}
__device__ __forceinline__ float bf2f(u16 h) {
  return __uint_as_float(((unsigned)h) << 16);
}
__device__ __forceinline__ void atomicMaxF(float* a, float v) {
  if (v >= 0.f) atomicMax((int*)a, __float_as_int(v));
  else          atomicMin((unsigned int*)a, __float_as_uint(v));
}
__device__ __forceinline__ float fq_u(float x) {           // unsigned 8-bit fake-quant
  float xc = fminf(fmaxf(x, 0.0f), 1.0f);
  return rintf(xc * 256.0f) * (1.0f / 256.0f);
}
__device__ __forceinline__ float fq_s(float x) {           // signed 8-bit fake-quant
  const float lim = 1.0f - 1.0f / 128.0f;
  float xc = fminf(fmaxf(x, -lim), lim);
  return rintf(xc * 128.0f) * (1.0f / 128.0f);
}
__device__ __forceinline__ float sigm(float x) { return 1.0f / (1.0f + expf(-x)); }

__device__ __forceinline__ void gload_lds16(const u16* g, u16* l) {
  __builtin_amdgcn_global_load_lds(
      (const __attribute__((address_space(1))) void*)g,
      (__attribute__((address_space(3))) void*)l, 16, 0, 0);
}

// ---------- prep1: split X hi/lo (independent) + max reductions (fused) ----------
// blocks [0,2048): X-split ; [2048,4100): maxes
__global__ __launch_bounds__(256) void k_prep1(
    const float* __restrict__ input, const float* __restrict__ hx,
    const float* __restrict__ w_ih, const float* __restrict__ w_hh,
    const float* __restrict__ b_ih, const float* __restrict__ b_hh,
    u16* __restrict__ Xhi, u16* __restrict__ Xlo, float* __restrict__ maxes) {
  const int bid = blockIdx.x;
  if (bid < 2048) {
    const int total4 = NB * KD / 4;
    for (int e4 = bid * 256 + threadIdx.x; e4 < total4; e4 += 2048 * 256) {
      int row = e4 >> 8;
      int c4  = e4 & 255;
      float4 v = (c4 < 128)
          ? reinterpret_cast<const float4*>(input)[row * 128 + c4]
          : reinterpret_cast<const float4*>(hx)[row * 128 + (c4 - 128)];
      float xs[4] = {v.x, v.y, v.z, v.w};
      ushort4 hi, lo;
      u16 h0 = f2bf(xs[0]); u16 l0 = f2bf(xs[0] - bf2f(h0));
      u16 h1 = f2bf(xs[1]); u16 l1 = f2bf(xs[1] - bf2f(h1));
      u16 h2 = f2bf(xs[2]); u16 l2 = f2bf(xs[2] - bf2f(h2));
      u16 h3 = f2bf(xs[3]); u16 l3 = f2bf(xs[3] - bf2f(h3));
      hi.x = h0; hi.y = h1; hi.z = h2; hi.w = h3;
      lo.x = l0; lo.y = l1; lo.z = l2; lo.w = l3;
      reinterpret_cast<ushort4*>(Xhi)[e4] = hi;
      reinterpret_cast<ushort4*>(Xlo)[e4] = lo;
    }
  } else {
    int mb = bid - 2048;
    const float* src; int slot, base;
    if (mb < 1024)      { src = w_ih; slot = 0; base = mb * 1024; }
    else if (mb < 2048) { src = w_hh; slot = 1; base = (mb - 1024) * 1024; }
    else if (mb < 2050) { src = b_ih; slot = 2; base = (mb - 2048) * 1024; }
    else                { src = b_hh; slot = 3; base = (mb - 2050) * 1024; }
    float m = -INFINITY;
    for (int i = threadIdx.x; i < 1024; i += 256) m = fmaxf(m, src[base + i]);
    for (int k = 1; k < 64; k <<= 1) m = fmaxf(m, __shfl_xor(m, k, 64));
    __shared__ float sm[4];
    if ((threadIdx.x & 63) == 0) sm[threadIdx.x >> 6] = m;
    __syncthreads();
    if (threadIdx.x == 0) {
      m = fmaxf(fmaxf(sm[0], sm[1]), fmaxf(sm[2], sm[3]));
      atomicMaxF(&maxes[slot], m);
    }
  }
}

// ---------- prep2: build W hi/lo (coalesced, LDS transpose) + combined bias ----------
// blocks [0,512): W (16 cols x 256 k each) ; [512,520): bias
// W physical j bits: [10:8]=bn, [7]=nh, [6:5]=wc, [4]=n2, [3:0]=lane
// gate g = 2*nh + n2 ; h-block hb = bn*4 + wc ; logical col = g*512 + hb*16 + j[3:0]
__global__ __launch_bounds__(256) void k_prep2(
    const float* __restrict__ w_ih, const float* __restrict__ w_hh,
    const float* __restrict__ n_ih, const float* __restrict__ n_hh,
    const float* __restrict__ b_ih, const float* __restrict__ b_hh,
    const float* __restrict__ nb_ih, const float* __restrict__ nb_hh,
    const float* __restrict__ maxes,
    u16* __restrict__ Whi, u16* __restrict__ Wlo, float* __restrict__ biasC) {
  const int bid = blockIdx.x;
  if (bid < 512) {
    __shared__ float nT[256][17];   // padded transpose buffer (17 KB)
    const int cg = bid >> 2, kb = bid & 3;
    const int j0 = cg * 16;
    const int g  = ((j0 >> 7) & 1) * 2 + ((j0 >> 4) & 1);
    const int hb = ((j0 >> 8) << 2) | ((j0 >> 5) & 3);
    const int col0 = g * 512 + (hb << 4);
    const int k0 = kb * 256;
    {
      const int cl = threadIdx.x & 15;
      const int kr = threadIdx.x >> 4;
#pragma unroll 4
      for (int i = 0; i < 16; ++i) {
        const int k = k0 + kr + 16 * i;
        nT[kr + 16 * i][cl] = (k < 512) ? n_ih[k * ND + col0 + cl]
                                        : n_hh[(k - 512) * ND + col0 + cl];
      }
    }
    __syncthreads();
    const float s_ih = maxes[0] * 0.1f, s_hh = maxes[1] * 0.1f;
    const int c  = threadIdx.x >> 4;
    const int kl = threadIdx.x & 15;
    const int colL = col0 + c;
    const int j = j0 + c;
#pragma unroll
    for (int kk = 0; kk < 4; ++kk) {
      const int k = k0 + kk * 64 + kl * 4;
      float4 wv; float s;
      if (k < 512) {
        wv = reinterpret_cast<const float4*>(w_ih)[(colL * 512 + k) >> 2];
        s = s_ih;
      } else {
        wv = reinterpret_cast<const float4*>(w_hh)[(colL * 512 + k - 512) >> 2];
        s = s_hh;
      }
      const int kt = k - k0;
      float xs[4] = {wv.x + nT[kt + 0][c] * s, wv.y + nT[kt + 1][c] * s,
                     wv.z + nT[kt + 2][c] * s, wv.w + nT[kt + 3][c] * s};
      ushort4 hi, lo;
      u16 h0 = f2bf(xs[0]); u16 l0 = f2bf(xs[0] - bf2f(h0));
      u16 h1 = f2bf(xs[1]); u16 l1 = f2bf(xs[1] - bf2f(h1));
      u16 h2 = f2bf(xs[2]); u16 l2 = f2bf(xs[2] - bf2f(h2));
      u16 h3 = f2bf(xs[3]); u16 l3 = f2bf(xs[3] - bf2f(h3));
      hi.x = h0; hi.y = h1; hi.z = h2; hi.w = h3;
      lo.x = l0; lo.y = l1; lo.z = l2; lo.w = l3;
      reinterpret_cast<ushort4*>(Whi)[(j * KD + k) >> 2] = hi;
      reinterpret_cast<ushort4*>(Wlo)[(j * KD + k) >> 2] = lo;
    }
  } else {
    int j = (bid - 512) * 256 + threadIdx.x;
    if (j < ND) {
      int g  = ((j >> 7) & 1) * 2 + ((j >> 4) & 1);
      int hb = ((j >> 8) << 2) | ((j >> 5) & 3);
      int col = g * 512 + (hb << 4) + (j & 15);
      biasC[j] = b_ih[col] + nb_ih[col] * (maxes[2] * 0.1f)
               + b_hh[col] + nb_hh[col] * (maxes[3] * 0.1f);
    }
  }
}

// ---------- GEMM: verbatim m201 8-phase template, segment-sequential K ----------
// 48 K64-steps: seg0 Xhi*Whi, seg1 Xlo*Whi, seg2 Xhi*Wlo (round-1 FP order).
// grid 256; 512 threads (8 waves 2x4); LDS 128K = [2 dbuf][A,B][2 half][128x64].
// Iteration = 2 tiles (even->slot0, odd->slot1), 8 phases; per phase:
//   {8A+4B / 4B / 8A / 0} ds_read_b128 + 1 half-tile stage (2 gload_lds, into a
//   dead region) + [lgkmcnt(8) if 12 reads] + s_barrier + lgkmcnt(0)
//   + sched_barrier(0) + setprio(1) + 16 MFMA + setprio(0) + s_barrier.
// vmcnt ONLY at ph4 (6) and ph8 (8); every waited load issued >=4 phases back.
// Stage calendar (unit deaths: Ah0@ph1, Bh0@ph1, Bh1@ph2, Ah1@ph3 + slot1 @5-7):
//   ph2:Ah0(T+2) ph3:Bh0(T+2) ph4:Bh1(T+2) ph5:Ah1(T+2)
//   ph6:Ah0(T+3) ph7:Bh0(T+3) ph8:Bh1(T+3)+Ah1(T+3)
__global__ __launch_bounds__(512, 2) void k_gemm_lstm(
    const u16* __restrict__ Xhi, const u16* __restrict__ Xlo,
    const u16* __restrict__ Whi, const u16* __restrict__ Wlo,
    const float* __restrict__ biasC, const float* __restrict__ cx,
    float* __restrict__ out) {
  __shared__ u16 L[2][2][2][8192];   // [slot][A=0/B=1][half][128 rows x 64 u16]
  const int tid  = threadIdx.x;
  const int lane = tid & 63, wid = tid >> 6;
  const int wr = wid >> 2, wc = wid & 3;       // 2 x 4 waves
  const int lr = lane & 15, lg = lane >> 4;
  const int l7 = lane & 7, l8 = lane >> 3;
  // XCD-region map: xcd = blk%8 owns an 8bm x 4bn region (bijective)
  const int xcd = blockIdx.x & 7, tt = blockIdx.x >> 3;
  const int bm = ((xcd >> 1) << 3) | (tt & 7);   // 0..31
  const int bn = ((xcd & 1) << 2) | (tt >> 3);   // 0..7
  const int mbase = bm * 256, nbase = bn * 256;

  // staging: thread -> row (g*64 + wid*8 + l8), dst chunk l7, src chunk l7^l8
  const int csrc = (l7 ^ l8) * 8;                 // u16 offset within 64-col row
  // frag read swizzle: LDS[r][c] = global[r][c ^ (r&7)]; r&7 == lr&7 everywhere

  f32x4 acc[8][4] = {};     // [mh*4+m2][gate = 2*nh+n2]
  bf16x8 afr[4][2];         // [m2][ks] current A m-half
  bf16x8 bfr[2][2][2];      // [nh][n2][ks], whole tile resident

#define STAGEH(V, SLOT, AB, HALF)                                             \
  {                                                                           \
    const int v_ = (V);                                                       \
    const int seg_ = v_ >> 4;                                                 \
    const u16* src_ = (AB) ? ((seg_ == 2) ? Wlo : Whi)                        \
                           : ((seg_ == 1) ? Xlo : Xhi);                       \
    const int kk_ = (v_ & 15) << 6;                                           \
    const int pb_ = ((AB) ? nbase : mbase) + (HALF) * 128;                    \
    gload_lds16(src_ + (size_t)(pb_ + wid * 8 + l8) * KD + kk_ + csrc,        \
                &L[SLOT][AB][HALF][(wid * 8) * 64]);                          \
    gload_lds16(src_ + (size_t)(pb_ + 64 + wid * 8 + l8) * KD + kk_ + csrc,   \
                &L[SLOT][AB][HALF][(64 + wid * 8) * 64]);                     \
  }

#define RD_A(S, MH)                                                           \
  _Pragma("unroll") for (int m2 = 0; m2 < 4; ++m2) {                          \
    const int rb_ = (wr * 64 + m2 * 16 + lr) * 64;                            \
    afr[m2][0] = *reinterpret_cast<const bf16x8*>(                            \
        &L[S][0][MH][rb_ + ((0 + lg) ^ (lr & 7)) * 8]);                       \
    afr[m2][1] = *reinterpret_cast<const bf16x8*>(                            \
        &L[S][0][MH][rb_ + ((4 + lg) ^ (lr & 7)) * 8]);                       \
  }

#define RD_B(S, NH)                                                           \
  _Pragma("unroll") for (int n2 = 0; n2 < 2; ++n2) {                          \
    const int rb_ = (wc * 32 + n2 * 16 + lr) * 64;                            \
    bfr[(NH)][n2][0] = *reinterpret_cast<const bf16x8*>(                      \
        &L[S][1][NH][rb_ + ((0 + lg) ^ (lr & 7)) * 8]);                       \
    bfr[(NH)][n2][1] = *reinterpret_cast<const bf16x8*>(                      \
        &L[S][1][NH][rb_ + ((4 + lg) ^ (lr & 7)) * 8]);                       \
  }

#define LG8 asm volatile("s_waitcnt lgkmcnt(8)" ::: "memory")
#define VM6 asm volatile("s_waitcnt vmcnt(6)" ::: "memory")
#define VM8 asm volatile("s_waitcnt vmcnt(8)" ::: "memory")
#define VM0 asm volatile("s_waitcnt vmcnt(0)" ::: "memory")

#define PH(S, MH, NH, RA, RB, STG, W12, WVM)                                  \
  {                                                                           \
    if (RA) { RD_A(S, MH) }                                                   \
    if (RB) { RD_B(S, NH) }                                                   \
    STG;                                                                      \
    W12;                                                                      \
    WVM;                                                                      \
    __builtin_amdgcn_s_barrier();                                             \
    asm volatile("s_waitcnt lgkmcnt(0)" ::: "memory");                        \
    __builtin_amdgcn_sched_barrier(0);                                        \
    __builtin_amdgcn_s_setprio(1);                                            \
    _Pragma("unroll") for (int ks = 0; ks < 2; ++ks)                          \
      _Pragma("unroll") for (int m2 = 0; m2 < 4; ++m2)                        \
        _Pragma("unroll") for (int n2 = 0; n2 < 2; ++n2) {                    \
          f32x4* ac = &acc[(MH) * 4 + m2][(NH) * 2 + n2];                     \
          *ac = __builtin_amdgcn_mfma_f32_16x16x32_bf16(                      \
              afr[m2][ks], bfr[(NH)][n2][ks], *ac, 0, 0, 0);                  \
        }                                                                     \
    __builtin_amdgcn_s_setprio(0);                                            \
    __builtin_amdgcn_s_barrier();                                             \
  }

  // prologue: tiles 0 (slot0) and 1 (slot1), unit order Ah0,Bh0,Bh1,Ah1
  STAGEH(0, 0, 0, 0); STAGEH(0, 0, 1, 0); STAGEH(0, 0, 1, 1); STAGEH(0, 0, 0, 1);
  STAGEH(1, 1, 0, 0); STAGEH(1, 1, 1, 0); STAGEH(1, 1, 1, 1); STAGEH(1, 1, 0, 1);
  VM8;                                     // tile 0 fully landed
  __builtin_amdgcn_s_barrier();

#pragma unroll 1
  for (int i = 0; i < 23; ++i) {           // tiles 0..45, staging 2..47
    const int T = 2 * i;
    PH(0, 0, 0, 1, 1, , LG8, )
    PH(0, 0, 1, 0, 1, STAGEH(T + 2, 0, 0, 0), , )
    PH(0, 1, 1, 1, 0, STAGEH(T + 2, 0, 1, 0), , )
    PH(0, 1, 0, 0, 0, STAGEH(T + 2, 0, 1, 1), , VM6)
    PH(1, 0, 0, 1, 1, STAGEH(T + 2, 0, 0, 1), LG8, )
    PH(1, 0, 1, 0, 1, STAGEH(T + 3, 1, 0, 0), , )
    PH(1, 1, 1, 1, 0, STAGEH(T + 3, 1, 1, 0), , )
    PH(1, 1, 0, 0, 0,
       { STAGEH(T + 3, 1, 1, 1); STAGEH(T + 3, 1, 0, 1); }, , VM8)
  }
  // tail: tiles 46 (slot0) and 47 (slot1), no staging
  PH(0, 0, 0, 1, 1, , LG8, )
  PH(0, 0, 1, 0, 1, , , )
  PH(0, 1, 1, 1, 0, , , )
  PH(0, 1, 0, 0, 0, , , VM0)
  PH(1, 0, 0, 1, 1, , LG8, )
  PH(1, 0, 1, 0, 1, , , )
  PH(1, 1, 1, 1, 0, , , )
  PH(1, 1, 0, 0, 0, , , )

#undef PH
#undef VM0
#undef VM8
#undef VM6
#undef LG8
#undef RD_B
#undef RD_A
#undef STAGEH

  // ---------- fused quantized-LSTM epilogue ----------
  const int hb = bn * 4 + wc;
  const int h = hb * 16 + lr;
  float bias[4];
#pragma unroll
  for (int g = 0; g < 4; ++g)
    bias[g] = biasC[bn * 256 + ((g >> 1) * 8 + wc * 2 + (g & 1)) * 16 + lr];
#pragma unroll
  for (int mh = 0; mh < 2; ++mh) {
#pragma unroll
    for (int m2 = 0; m2 < 4; ++m2) {
      const int m = mh * 4 + m2;
#pragma unroll
      for (int r = 0; r < 4; ++r) {
        const int row = mbase + mh * 128 + wr * 64 + m2 * 16 + lg * 4 + r;
        const float gi = acc[m][0][r] + bias[0];
        const float gf = acc[m][1][r] + bias[1];
        const float gc = acc[m][2][r] + bias[2];
        const float go = acc[m][3][r] + bias[3];
        const float ig = fq_u(sigm(gi));
        const float fg = fq_u(sigm(gf));
        const float cg = fq_s(tanhf(gc));
        const float og = fq_u(sigm(go));
        const float cxv = cx[(size_t)row * HD + h];
        const float t1 = fq_s(fg * cxv);
        const float t2 = fq_s(ig * cg);
        const float cyv = fq_s((t1 + t2) * 0.5f);
        const float hyv = fq_s(og * fq_s(tanhf(cyv * 2.0f)));
        out[(size_t)row * HD + h] = hyv;
        out[HY_OFF + (size_t)row * HD + h] = cyv;
      }
    }
  }
}

// ---------- launch ----------
extern "C" void kernel_launch(void* const* d_in, const int* in_sizes, int n_in,
                              void* d_out, int out_size, void* d_ws, size_t ws_size,
                              hipStream_t stream) {
  const float* input = (const float*)d_in[0];
  const float* hx    = (const float*)d_in[1];
  const float* cx    = (const float*)d_in[2];
  const float* w_ih  = (const float*)d_in[3];
  const float* w_hh  = (const float*)d_in[4];
  const float* b_ih  = (const float*)d_in[5];
  const float* b_hh  = (const float*)d_in[6];
  const float* n_ih  = (const float*)d_in[7];
  const float* n_hh  = (const float*)d_in[8];
  const float* nb_ih = (const float*)d_in[9];
  const float* nb_hh = (const float*)d_in[10];
  float* out = (float*)d_out;

  char* ws = (char*)d_ws;
  float* maxes = (float*)ws;                                   // 16 B (+pad to 256)
  u16* Xhi = (u16*)(ws + 256);                                 // 16 MB
  u16* Xlo = (u16*)(ws + 256 + 16777216);                      // 16 MB
  u16* Whi = (u16*)(ws + 256 + 2 * 16777216);                  // 4 MB
  u16* Wlo = (u16*)(ws + 256 + 2 * 16777216 + 4194304);        // 4 MB
  float* biasC = (float*)(ws + 256 + 2 * 16777216 + 2 * 4194304); // 8 KB

  hipMemsetAsync(maxes, 0xFF, 16, stream);  // -NaN sentinel; atomic lattice fixes it
  hipLaunchKernelGGL(k_prep1, dim3(4100), dim3(256), 0, stream,
                     input, hx, w_ih, w_hh, b_ih, b_hh, Xhi, Xlo, maxes);
  hipLaunchKernelGGL(k_prep2, dim3(520), dim3(256), 0, stream,
                     w_ih, w_hh, n_ih, n_hh, b_ih, b_hh, nb_ih, nb_hh,
                     maxes, Whi, Wlo, biasC);
  hipLaunchKernelGGL(k_gemm_lstm, dim3(256), dim3(512), 0, stream,
                     Xhi, Xlo, Whi, Wlo, biasC, cx, out);
}

// Round 12
// 146.892 us; speedup vs baseline: 1.0118x; 1.0118x over previous
//
#include <hip/hip_runtime.h>
#include <cstdint>

typedef unsigned short u16;
typedef __bf16 bf16x8 __attribute__((ext_vector_type(8)));
typedef float f32x4 __attribute__((ext_vector_type(4)));

#define NB 8192          // batch rows
#define HD 512           // hidden
#define KD 1024          // IN + H
#define ND 2048          // 4H (physical, column-reordered)
#define HY_OFF (NB * HD) // offset of cy in d_out

// ---------- helpers ----------
__device__ __forceinline__ u16 f2bf(float f) {
  unsigned u = __float_as_uint(f);
  u += 0x7FFFu + ((u >> 16) & 1u);          // round-to-nearest-even bf16
  return (u16)(u >> 16);
}
__device__ __forceinline__ float bf2f(u16 h) {
  return __uint_as_float(((unsigned)h) << 16);
}
__device__ __forceinline__ void atomicMaxF(float* a, float v) {
  if (v >= 0.f) atomicMax((int*)a, __float_as_int(v));
  else          atomicMin((unsigned int*)a, __float_as_uint(v));
}
__device__ __forceinline__ float fq_u(float x) {           // unsigned 8-bit fake-quant
  float xc = fminf(fmaxf(x, 0.0f), 1.0f);
  return rintf(xc * 256.0f) * (1.0f / 256.0f);
}
__device__ __forceinline__ float fq_s(float x) {           // signed 8-bit fake-quant
  const float lim = 1.0f - 1.0f / 128.0f;
  float xc = fminf(fmaxf(x, -lim), lim);
  return rintf(xc * 128.0f) * (1.0f / 128.0f);
}
__device__ __forceinline__ float sigm(float x) { return 1.0f / (1.0f + expf(-x)); }

__device__ __forceinline__ void gload_lds16(const u16* g, u16* l) {
  __builtin_amdgcn_global_load_lds(
      (const __attribute__((address_space(1))) void*)g,
      (__attribute__((address_space(3))) void*)l, 16, 0, 0);
}

// ---------- prep1: split X hi/lo + max reductions (fused) ----------
__global__ __launch_bounds__(256) void k_prep1(
    const float* __restrict__ input, const float* __restrict__ hx,
    const float* __restrict__ w_ih, const float* __restrict__ w_hh,
    const float* __restrict__ b_ih, const float* __restrict__ b_hh,
    u16* __restrict__ Xhi, u16* __restrict__ Xlo, float* __restrict__ maxes) {
  const int bid = blockIdx.x;
  if (bid < 2048) {
    const int total4 = NB * KD / 4;
    for (int e4 = bid * 256 + threadIdx.x; e4 < total4; e4 += 2048 * 256) {
      int row = e4 >> 8;
      int c4  = e4 & 255;
      float4 v = (c4 < 128)
          ? reinterpret_cast<const float4*>(input)[row * 128 + c4]
          : reinterpret_cast<const float4*>(hx)[row * 128 + (c4 - 128)];
      float xs[4] = {v.x, v.y, v.z, v.w};
      ushort4 hi, lo;
      u16 h0 = f2bf(xs[0]); u16 l0 = f2bf(xs[0] - bf2f(h0));
      u16 h1 = f2bf(xs[1]); u16 l1 = f2bf(xs[1] - bf2f(h1));
      u16 h2 = f2bf(xs[2]); u16 l2 = f2bf(xs[2] - bf2f(h2));
      u16 h3 = f2bf(xs[3]); u16 l3 = f2bf(xs[3] - bf2f(h3));
      hi.x = h0; hi.y = h1; hi.z = h2; hi.w = h3;
      lo.x = l0; lo.y = l1; lo.z = l2; lo.w = l3;
      reinterpret_cast<ushort4*>(Xhi)[e4] = hi;
      reinterpret_cast<ushort4*>(Xlo)[e4] = lo;
    }
  } else {
    int mb = bid - 2048;
    const float* src; int slot, base;
    if (mb < 1024)      { src = w_ih; slot = 0; base = mb * 1024; }
    else if (mb < 2048) { src = w_hh; slot = 1; base = (mb - 1024) * 1024; }
    else if (mb < 2050) { src = b_ih; slot = 2; base = (mb - 2048) * 1024; }
    else                { src = b_hh; slot = 3; base = (mb - 2050) * 1024; }
    float m = -INFINITY;
    for (int i = threadIdx.x; i < 1024; i += 256) m = fmaxf(m, src[base + i]);
    for (int k = 1; k < 64; k <<= 1) m = fmaxf(m, __shfl_xor(m, k, 64));
    __shared__ float sm[4];
    if ((threadIdx.x & 63) == 0) sm[threadIdx.x >> 6] = m;
    __syncthreads();
    if (threadIdx.x == 0) {
      m = fmaxf(fmaxf(sm[0], sm[1]), fmaxf(sm[2], sm[3]));
      atomicMaxF(&maxes[slot], m);
    }
  }
}

// ---------- prep2: build W hi/lo (coalesced, LDS transpose) + combined bias ----------
__global__ __launch_bounds__(256) void k_prep2(
    const float* __restrict__ w_ih, const float* __restrict__ w_hh,
    const float* __restrict__ n_ih, const float* __restrict__ n_hh,
    const float* __restrict__ b_ih, const float* __restrict__ b_hh,
    const float* __restrict__ nb_ih, const float* __restrict__ nb_hh,
    const float* __restrict__ maxes,
    u16* __restrict__ Whi, u16* __restrict__ Wlo, float* __restrict__ biasC) {
  const int bid = blockIdx.x;
  if (bid < 512) {
    __shared__ float nT[256][17];
    const int cg = bid >> 2, kb = bid & 3;
    const int j0 = cg * 16;
    const int g  = ((j0 >> 7) & 1) * 2 + ((j0 >> 4) & 1);
    const int hb = ((j0 >> 8) << 2) | ((j0 >> 5) & 3);
    const int col0 = g * 512 + (hb << 4);
    const int k0 = kb * 256;
    {
      const int cl = threadIdx.x & 15;
      const int kr = threadIdx.x >> 4;
#pragma unroll 4
      for (int i = 0; i < 16; ++i) {
        const int k = k0 + kr + 16 * i;
        nT[kr + 16 * i][cl] = (k < 512) ? n_ih[k * ND + col0 + cl]
                                        : n_hh[(k - 512) * ND + col0 + cl];
      }
    }
    __syncthreads();
    const float s_ih = maxes[0] * 0.1f, s_hh = maxes[1] * 0.1f;
    const int c  = threadIdx.x >> 4;
    const int kl = threadIdx.x & 15;
    const int colL = col0 + c;
    const int j = j0 + c;
#pragma unroll
    for (int kk = 0; kk < 4; ++kk) {
      const int k = k0 + kk * 64 + kl * 4;
      float4 wv; float s;
      if (k < 512) {
        wv = reinterpret_cast<const float4*>(w_ih)[(colL * 512 + k) >> 2];
        s = s_ih;
      } else {
        wv = reinterpret_cast<const float4*>(w_hh)[(colL * 512 + k - 512) >> 2];
        s = s_hh;
      }
      const int kt = k - k0;
      float xs[4] = {wv.x + nT[kt + 0][c] * s, wv.y + nT[kt + 1][c] * s,
                     wv.z + nT[kt + 2][c] * s, wv.w + nT[kt + 3][c] * s};
      ushort4 hi, lo;
      u16 h0 = f2bf(xs[0]); u16 l0 = f2bf(xs[0] - bf2f(h0));
      u16 h1 = f2bf(xs[1]); u16 l1 = f2bf(xs[1] - bf2f(h1));
      u16 h2 = f2bf(xs[2]); u16 l2 = f2bf(xs[2] - bf2f(h2));
      u16 h3 = f2bf(xs[3]); u16 l3 = f2bf(xs[3] - bf2f(h3));
      hi.x = h0; hi.y = h1; hi.z = h2; hi.w = h3;
      lo.x = l0; lo.y = l1; lo.z = l2; lo.w = l3;
      reinterpret_cast<ushort4*>(Whi)[(j * KD + k) >> 2] = hi;
      reinterpret_cast<ushort4*>(Wlo)[(j * KD + k) >> 2] = lo;
    }
  } else {
    int j = (bid - 512) * 256 + threadIdx.x;
    if (j < ND) {
      int g  = ((j >> 7) & 1) * 2 + ((j >> 4) & 1);
      int hb = ((j >> 8) << 2) | ((j >> 5) & 3);
      int col = g * 512 + (hb << 4) + (j & 15);
      biasC[j] = b_ih[col] + nb_ih[col] * (maxes[2] * 0.1f)
               + b_hh[col] + nb_hh[col] * (maxes[3] * 0.1f);
    }
  }
}

// ---------- GEMM: m201 8-phase, OPAQUE asm ds_reads (no compiler alias edge) ----------
// Layout L2[ab][half][slot][8192 u16]: A base 0, B base 65536B; half stride
// 32768B; slot stride 16384B -> slot+m2 offsets fit the 16-bit ds offset field.
// Frag reads are inline-asm ds_read_b128 on precomputed addrspace(3) addresses:
// the compiler sees NO LDS dependence between global_load_lds staging and the
// reads, so it cannot insert hidden vmcnt drains -- ordering is exactly the
// hand ledger: VM6@ph4 / VM8@ph8 (every waited load issued >=4 phases back),
// barriers separate all WAR edges (each phase's reads drain at its lgkmcnt(0)
// before its trailing barrier). Rule 18: lgkmcnt(0)+sched_barrier(0) precede
// each MFMA cluster (MFMAs consume asm outputs).
__global__ __launch_bounds__(512, 2) void k_gemm_lstm(
    const u16* __restrict__ Xhi, const u16* __restrict__ Xlo,
    const u16* __restrict__ Whi, const u16* __restrict__ Wlo,
    const float* __restrict__ biasC, const float* __restrict__ cx,
    float* __restrict__ out) {
  __shared__ u16 L2[2][2][2][8192];   // [ab][half][slot][128 rows x 64 u16]
  const int tid  = threadIdx.x;
  const int lane = tid & 63, wid = tid >> 6;
  const int wr = wid >> 2, wc = wid & 3;       // 2 x 4 waves
  const int lr = lane & 15, lg = lane >> 4;
  const int l7 = lane & 7, l8 = lane >> 3;
  // XCD-region map: xcd = blk%8 owns an 8bm x 4bn region (bijective)
  const int xcd = blockIdx.x & 7, tt = blockIdx.x >> 3;
  const int bm = ((xcd >> 1) << 3) | (tt & 7);   // 0..31
  const int bn = ((xcd & 1) << 2) | (tt >> 3);   // 0..7
  const int mbase = bm * 256, nbase = bn * 256;

  // staging: thread -> row (wid*8 + l8), dst chunk l7, src chunk l7^l8
  const int csrc = (l7 ^ l8) * 8;                 // u16 offset in 64-col row

  // LDS base as a 32-bit addrspace(3) offset (avoid generic-aperture cast)
  const unsigned lbase =
      (unsigned)(uintptr_t)(__attribute__((address_space(3))) u16*)&L2[0][0][0][0];
  unsigned a_ad[2][2], b_ad[2][2];   // [half][ks]
#pragma unroll
  for (int h = 0; h < 2; ++h)
#pragma unroll
    for (int ks = 0; ks < 2; ++ks) {
      const int ch = ((ks << 2) | lg) ^ (lr & 7);
      a_ad[h][ks] = lbase + h * 32768 + (wr * 64 + lr) * 128 + ch * 16;
      b_ad[h][ks] = lbase + 65536 + h * 32768 + (wc * 32 + lr) * 128 + ch * 16;
    }

  f32x4 acc[8][4] = {};     // [mh*4+m2][gate = 2*nh+n2]
  bf16x8 afr[4][2];         // [m2][ks]
  bf16x8 bfr[2][2][2];      // [nh][n2][ks]

#define DSR(D, A, OFF)                                                        \
  asm volatile("ds_read_b128 %0, %1 offset:" #OFF : "=v"(D) : "v"(A))

// 8 A-frag reads: m2 offsets 0/2048/4096/6144 (+16384 for slot1)
#define RDA(MH, O0, O1, O2, O3)                                               \
  { DSR(afr[0][0], a_ad[MH][0], O0); DSR(afr[1][0], a_ad[MH][0], O1);         \
    DSR(afr[2][0], a_ad[MH][0], O2); DSR(afr[3][0], a_ad[MH][0], O3);         \
    DSR(afr[0][1], a_ad[MH][1], O0); DSR(afr[1][1], a_ad[MH][1], O1);         \
    DSR(afr[2][1], a_ad[MH][1], O2); DSR(afr[3][1], a_ad[MH][1], O3); }
// 4 B-frag reads: n2 offsets 0/2048 (+16384 for slot1)
#define RDB(NH, O0, O1)                                                       \
  { DSR(bfr[NH][0][0], b_ad[NH][0], O0); DSR(bfr[NH][1][0], b_ad[NH][0], O1); \
    DSR(bfr[NH][0][1], b_ad[NH][1], O0); DSR(bfr[NH][1][1], b_ad[NH][1], O1); }

#define STAGEH(V, SLOT, AB, HALF)                                             \
  {                                                                           \
    const int v_ = (V);                                                       \
    const int seg_ = v_ >> 4;                                                 \
    const u16* src_ = (AB) ? ((seg_ == 2) ? Wlo : Whi)                        \
                           : ((seg_ == 1) ? Xlo : Xhi);                       \
    const int kk_ = (v_ & 15) << 6;                                           \
    const int pb_ = ((AB) ? nbase : mbase) + (HALF) * 128;                    \
    u16* d_ = &L2[AB][HALF][SLOT][(wid * 8) * 64];                            \
    gload_lds16(src_ + (size_t)(pb_ + wid * 8 + l8) * KD + kk_ + csrc, d_);   \
    gload_lds16(src_ + (size_t)(pb_ + 64 + wid * 8 + l8) * KD + kk_ + csrc,   \
                d_ + 4096);                                                   \
  }

#define LG8 asm volatile("s_waitcnt lgkmcnt(8)" ::: "memory")
#define VM6 asm volatile("s_waitcnt vmcnt(6)" ::: "memory")
#define VM8 asm volatile("s_waitcnt vmcnt(8)" ::: "memory")
#define VM0 asm volatile("s_waitcnt vmcnt(0)" ::: "memory")

#define PH(MH, NH, READS, STG, W12, WVM)                                      \
  {                                                                           \
    READS;                                                                    \
    STG;                                                                      \
    W12;                                                                      \
    WVM;                                                                      \
    __builtin_amdgcn_s_barrier();                                             \
    asm volatile("s_waitcnt lgkmcnt(0)" ::: "memory");                        \
    __builtin_amdgcn_sched_barrier(0);                                        \
    __builtin_amdgcn_s_setprio(1);                                            \
    _Pragma("unroll") for (int ks = 0; ks < 2; ++ks)                          \
      _Pragma("unroll") for (int m2 = 0; m2 < 4; ++m2)                        \
        _Pragma("unroll") for (int n2 = 0; n2 < 2; ++n2) {                    \
          f32x4* ac = &acc[(MH) * 4 + m2][(NH) * 2 + n2];                     \
          *ac = __builtin_amdgcn_mfma_f32_16x16x32_bf16(                      \
              afr[m2][ks], bfr[(NH)][n2][ks], *ac, 0, 0, 0);                  \
        }                                                                     \
    __builtin_amdgcn_s_setprio(0);                                            \
    __builtin_amdgcn_s_barrier();                                             \
  }

  // prologue: tiles 0 (slot0) and 1 (slot1), unit order Ah0,Bh0,Bh1,Ah1
  STAGEH(0, 0, 0, 0); STAGEH(0, 0, 1, 0); STAGEH(0, 0, 1, 1); STAGEH(0, 0, 0, 1);
  STAGEH(1, 1, 0, 0); STAGEH(1, 1, 1, 0); STAGEH(1, 1, 1, 1); STAGEH(1, 1, 0, 1);
  VM8;                                     // tile 0 fully landed
  __builtin_amdgcn_s_barrier();

#pragma unroll 1
  for (int i = 0; i < 23; ++i) {           // tiles 0..45, staging 2..47
    const int T = 2 * i;
    // tile T (slot 0)
    PH(0, 0, { RDA(0, 0, 2048, 4096, 6144) RDB(0, 0, 2048) }, , LG8, )
    PH(0, 1, { RDB(1, 0, 2048) },            STAGEH(T + 2, 0, 0, 0), , )
    PH(1, 1, { RDA(1, 0, 2048, 4096, 6144) },STAGEH(T + 2, 0, 1, 0), , )
    PH(1, 0, { },                            STAGEH(T + 2, 0, 1, 1), , VM6)
    // tile T+1 (slot 1)
    PH(0, 0, { RDA(0, 16384, 18432, 20480, 22528) RDB(0, 16384, 18432) },
       STAGEH(T + 2, 0, 0, 1), LG8, )
    PH(0, 1, { RDB(1, 16384, 18432) },       STAGEH(T + 3, 1, 0, 0), , )
    PH(1, 1, { RDA(1, 16384, 18432, 20480, 22528) },
       STAGEH(T + 3, 1, 1, 0), , )
    PH(1, 0, { },
       { STAGEH(T + 3, 1, 1, 1); STAGEH(T + 3, 1, 0, 1); }, , VM8)
  }
  // tail: tiles 46 (slot0) and 47 (slot1), no staging
  PH(0, 0, { RDA(0, 0, 2048, 4096, 6144) RDB(0, 0, 2048) }, , LG8, )
  PH(0, 1, { RDB(1, 0, 2048) }, , , )
  PH(1, 1, { RDA(1, 0, 2048, 4096, 6144) }, , , )
  PH(1, 0, { }, , , VM0)
  PH(0, 0, { RDA(0, 16384, 18432, 20480, 22528) RDB(0, 16384, 18432) }, , LG8, )
  PH(0, 1, { RDB(1, 16384, 18432) }, , , )
  PH(1, 1, { RDA(1, 16384, 18432, 20480, 22528) }, , , )
  PH(1, 0, { }, , , )

#undef PH
#undef VM0
#undef VM8
#undef VM6
#undef LG8
#undef STAGEH
#undef RDB
#undef RDA
#undef DSR

  // ---------- fused quantized-LSTM epilogue ----------
  const int hb = bn * 4 + wc;
  const int h = hb * 16 + lr;
  float bias[4];
#pragma unroll
  for (int g = 0; g < 4; ++g)
    bias[g] = biasC[bn * 256 + ((g >> 1) * 8 + wc * 2 + (g & 1)) * 16 + lr];
#pragma unroll
  for (int mh = 0; mh < 2; ++mh) {
#pragma unroll
    for (int m2 = 0; m2 < 4; ++m2) {
      const int m = mh * 4 + m2;
#pragma unroll
      for (int r = 0; r < 4; ++r) {
        const int row = mbase + mh * 128 + wr * 64 + m2 * 16 + lg * 4 + r;
        const float gi = acc[m][0][r] + bias[0];
        const float gf = acc[m][1][r] + bias[1];
        const float gc = acc[m][2][r] + bias[2];
        const float go = acc[m][3][r] + bias[3];
        const float ig = fq_u(sigm(gi));
        const float fg = fq_u(sigm(gf));
        const float cg = fq_s(tanhf(gc));
        const float og = fq_u(sigm(go));
        const float cxv = cx[(size_t)row * HD + h];
        const float t1 = fq_s(fg * cxv);
        const float t2 = fq_s(ig * cg);
        const float cyv = fq_s((t1 + t2) * 0.5f);
        const float hyv = fq_s(og * fq_s(tanhf(cyv * 2.0f)));
        out[(size_t)row * HD + h] = hyv;
        out[HY_OFF + (size_t)row * HD + h] = cyv;
      }
    }
  }
}

// ---------- launch ----------
extern "C" void kernel_launch(void* const* d_in, const int* in_sizes, int n_in,
                              void* d_out, int out_size, void* d_ws, size_t ws_size,
                              hipStream_t stream) {
  const float* input = (const float*)d_in[0];
  const float* hx    = (const float*)d_in[1];
  const float* cx    = (const float*)d_in[2];
  const float* w_ih  = (const float*)d_in[3];
  const float* w_hh  = (const float*)d_in[4];
  const float* b_ih  = (const float*)d_in[5];
  const float* b_hh  = (const float*)d_in[6];
  const float* n_ih  = (const float*)d_in[7];
  const float* n_hh  = (const float*)d_in[8];
  const float* nb_ih = (const float*)d_in[9];
  const float* nb_hh = (const float*)d_in[10];
  float* out = (float*)d_out;

  char* ws = (char*)d_ws;
  float* maxes = (float*)ws;                                   // 16 B (+pad to 256)
  u16* Xhi = (u16*)(ws + 256);                                 // 16 MB
  u16* Xlo = (u16*)(ws + 256 + 16777216);                      // 16 MB
  u16* Whi = (u16*)(ws + 256 + 2 * 16777216);                  // 4 MB
  u16* Wlo = (u16*)(ws + 256 + 2 * 16777216 + 4194304);        // 4 MB
  float* biasC = (float*)(ws + 256 + 2 * 16777216 + 2 * 4194304); // 8 KB

  hipMemsetAsync(maxes, 0xFF, 16, stream);  // -NaN sentinel; atomic lattice fixes it
  hipLaunchKernelGGL(k_prep1, dim3(4100), dim3(256), 0, stream,
                     input, hx, w_ih, w_hh, b_ih, b_hh, Xhi, Xlo, maxes);
  hipLaunchKernelGGL(k_prep2, dim3(520), dim3(256), 0, stream,
                     w_ih, w_hh, n_ih, n_hh, b_ih, b_hh, nb_ih, nb_hh,
                     maxes, Whi, Wlo, biasC);
  hipLaunchKernelGGL(k_gemm_lstm, dim3(256), dim3(512), 0, stream,
                     Xhi, Xlo, Whi, Wlo, biasC, cx, out);
}